// Round 7
// baseline (158.253 us; speedup 1.0000x reference)
//
#include <hip/hip_runtime.h>

typedef __bf16 bf16;
typedef bf16 bf16x2 __attribute__((ext_vector_type(2)));
typedef bf16 bf16x4 __attribute__((ext_vector_type(4)));
typedef bf16 bf16x8 __attribute__((ext_vector_type(8)));
typedef float f32x4 __attribute__((ext_vector_type(4)));
typedef float f32x16 __attribute__((ext_vector_type(16)));
typedef int i32x2 __attribute__((ext_vector_type(2)));
typedef int i32x4 __attribute__((ext_vector_type(4)));

#define SEQ 256
#define DH  32
#define VT_PAD 264   // bf16 row stride 528B = 33*16B
#define KB_PAD 40    // bf16 row stride  80B =  5*16B
#define TRP 36       // tri tile padded cols (floats): 144B row, 16B-aligned

// pack two f32 -> one dword of 2 bf16 (v_cvt_pk_bf16_f32)
static __device__ __forceinline__ int pk2(float a, float b) {
    bf16x2 t; t[0] = (bf16)a; t[1] = (bf16)b;
    return __builtin_bit_cast(int, t);
}

static __device__ __forceinline__ bf16x8 cvt8(f32x4 a, f32x4 b) {
    bf16x8 f;
    f[0]=(bf16)a[0]; f[1]=(bf16)a[1]; f[2]=(bf16)a[2]; f[3]=(bf16)a[3];
    f[4]=(bf16)b[0]; f[5]=(bf16)b[1]; f[6]=(bf16)b[2]; f[7]=(bf16)b[3];
    return f;
}

// One C-register group G of the 32x32 QK^T output -> exp2 -> two packed dwords
// covering t = 8G+4hi+{0..3}. All indices compile-time.
template<int G>
static __device__ __forceinline__ i32x2 pgrp(f32x16 cf, f32x4 tg, f32x4 mk, float& lp) {
    constexpr float K1    = 0.17677669529663687f * 1.44269504088896f; // sm_scale*log2e
    constexpr float LOG2E = 1.44269504088896f;
    float p0 = __builtin_amdgcn_exp2f(fmaf(cf[4*G+0], K1, fmaf(tg[0], LOG2E, mk[0])));
    float p1 = __builtin_amdgcn_exp2f(fmaf(cf[4*G+1], K1, fmaf(tg[1], LOG2E, mk[1])));
    float p2 = __builtin_amdgcn_exp2f(fmaf(cf[4*G+2], K1, fmaf(tg[2], LOG2E, mk[2])));
    float p3 = __builtin_amdgcn_exp2f(fmaf(cf[4*G+3], K1, fmaf(tg[3], LOG2E, mk[3])));
    lp += (p0 + p1) + (p2 + p3);
    i32x2 r; r[0] = pk2(p0, p1); r[1] = pk2(p2, p3);
    return r;
}

// 4 permlane32_swap -> two PV A-frags (t-local 0..15 and 16..31)
static __device__ __forceinline__ void frags(i32x2 a0, i32x2 a1, i32x2 a2, i32x2 a3,
                                             bf16x8& f0, bf16x8& f1) {
    i32x2 s0 = __builtin_amdgcn_permlane32_swap(a0[0], a1[0], false, false);
    i32x2 s1 = __builtin_amdgcn_permlane32_swap(a0[1], a1[1], false, false);
    i32x2 s2 = __builtin_amdgcn_permlane32_swap(a2[0], a3[0], false, false);
    i32x2 s3 = __builtin_amdgcn_permlane32_swap(a2[1], a3[1], false, false);
    i32x4 w0 = {s0[0], s1[0], s0[1], s1[1]};
    i32x4 w1 = {s2[0], s3[0], s2[1], s3[1]};
    f0 = __builtin_bit_cast(bf16x8, w0);
    f1 = __builtin_bit_cast(bf16x8, w1);
}

// wave-private tri tile (32 rows x 32 cols, chunk cc) -> 4 named regs.
// Coalesced: instr i covers 8 rows, each a dense 128B segment.
#define LOAD_TRI(cc)                                              \
    sA = *(const f32x4*)(tstage + (cc) * 32 + 0 * 8 * SEQ);       \
    sB = *(const f32x4*)(tstage + (cc) * 32 + 1 * 8 * SEQ);       \
    sC = *(const f32x4*)(tstage + (cc) * 32 + 2 * 8 * SEQ);       \
    sD = *(const f32x4*)(tstage + (cc) * 32 + 3 * 8 * SEQ);

#define STORE_TRI()                                               \
    *(f32x4*)(twr + 0 * 8 * TRP) = sA;                            \
    *(f32x4*)(twr + 1 * 8 * TRP) = sB;                            \
    *(f32x4*)(twr + 2 * 8 * TRP) = sC;                            \
    *(f32x4*)(twr + 3 * 8 * TRP) = sD;

// S^T = K*Q^T with 32x32x16 MFMAs (M=t keys, N=s queries).
// C layout: col = s = lane&31, row = t = (reg&3) + 8*(reg>>2) + 4*(lane>>5).
// Topology: 1 block per (n,h); 8 waves x 32 queries (1 stile each).
// Same LDS as R6 (75.3KB -> 2 blocks/CU) amortized over 2x the waves:
// 16 waves/CU = 4/SIMD (R6 measured 1.4/SIMD time-avg -> latency exposed).
// tri bias: coalesced global->reg->wave-private LDS tile, 2 chunks ahead,
// no barriers (same-wave DS ordering gives read-before-overwrite).
// NOTE: min-waves/EU=2 in launch_bounds: higher values squeeze VGPRs ->
// scratch spill (R1: 456MB, R3: 235MB phantom WRITE_SIZE).
__global__ __launch_bounds__(512, 2) void attn_mfma_kernel(
    const float* __restrict__ q,
    const float* __restrict__ k,
    const float* __restrict__ v,
    const float* __restrict__ mask_bias,   // [N][SEQ]
    const float* __restrict__ tri_bias,    // [H][SEQ][SEQ]
    float* __restrict__ out)
{
    __shared__ __align__(16) bf16  Vt[DH][VT_PAD];   // V^T bf16: 16896 B
    __shared__ __align__(16) bf16  Kb[SEQ][KB_PAD];  // K bf16:   20480 B
    __shared__ __align__(16) float Ml[SEQ];          //            1024 B
    __shared__ __align__(16) float Tr[8][32][TRP];   // tri tiles: 36864 B (75.3 KB)

    const int tid  = threadIdx.x;
    const int wave = tid >> 6;             // 0..7
    const int lane = tid & 63;
    const int l31  = lane & 31;
    const int hi   = lane >> 5;

    const int inst = blockIdx.x;           // n*4 + h
    const int n    = inst >> 2;
    const int h    = inst & 3;

    const float* qb = q + (size_t)inst * SEQ * DH;
    const float* kb = k + (size_t)inst * SEQ * DH;
    const float* vb = v + (size_t)inst * SEQ * DH;
    const float* mb = mask_bias + (size_t)n * SEQ;
    const float* tb = tri_bias + (size_t)h * SEQ * SEQ;

    constexpr float LOG2E = 1.44269504088896f;

    const int qbase = wave * 32;           // this wave's 32 queries (1 stile)

    // coalesced tri staging: lane covers row qbase+(lane>>3)+8i, 16B col (lane&7)
    const float* tstage = tb + (size_t)(qbase + (lane >> 3)) * SEQ + (lane & 7) * 4;
    float*       twr    = &Tr[wave][lane >> 3][(lane & 7) * 4];

    f32x4 sA, sB, sC, sD;

    // ---- issue chunk0 tri loads first (in flight across all staging) ----
    LOAD_TRI(0);

    // ---- Q b-frags: qfD = Q[qbase+l31][D*16 + hi*8 .. +7] ----
    bf16x8 qf0, qf1;
    {
        const float* p = qb + (size_t)(qbase + l31) * DH + hi * 8;
        qf0 = cvt8(((const f32x4*)p)[0], ((const f32x4*)p)[1]);
        qf1 = cvt8(((const f32x4*)(p + 16))[0], ((const f32x4*)(p + 16))[1]);
    }

    // ---- stage V^T (bf16), K (bf16), mask*log2e into LDS (512 threads) ----
    #pragma unroll
    for (int i = 0; i < 4; ++i) {
        int idx = i * 512 + tid;           // float4 index: t = idx>>3, d-group = idx&7
        int t   = idx >> 3;
        int d4  = (idx & 7) * 4;
        f32x4 tv = ((const f32x4*)vb)[idx];
        Vt[d4 + 0][t] = (bf16)tv[0];
        Vt[d4 + 1][t] = (bf16)tv[1];
        Vt[d4 + 2][t] = (bf16)tv[2];
        Vt[d4 + 3][t] = (bf16)tv[3];
        f32x4 tk = ((const f32x4*)kb)[idx];
        bf16x4 kk;
        kk[0]=(bf16)tk[0]; kk[1]=(bf16)tk[1]; kk[2]=(bf16)tk[2]; kk[3]=(bf16)tk[3];
        *(bf16x4*)&Kb[t][d4] = kk;
    }
    if (tid < SEQ) Ml[tid] = mb[tid] * LOG2E;

    // write tri chunk0 tile, then start chunk1 loads (wave-local, no barrier)
    STORE_TRI();
    LOAD_TRI(1);

    __syncthreads();                       // for Vt/Kb/Ml only

    f32x16 oacc = {};
    float lp = 0.f;
    const f32x16 z16 = {};

    // ---- main loop: 8 chunks of 32 keys ----
    for (int c = 0; c < 8; ++c) {
        const int tb0 = c * 32;

        // tri for chunk c from wave-private LDS tile
        const float* trd = &Tr[wave][l31][hi * 4];     // col floats 8g+4hi
        f32x4 t0 = *(const f32x4*)(trd + 0);
        f32x4 t1 = *(const f32x4*)(trd + 8);
        f32x4 t2 = *(const f32x4*)(trd + 16);
        f32x4 t3 = *(const f32x4*)(trd + 24);

        // K a-frags + V b-frags from LDS
        bf16x8 kf0 = *(const bf16x8*)&Kb[tb0 + l31][hi * 8];
        bf16x8 kf1 = *(const bf16x8*)&Kb[tb0 + l31][16 + hi * 8];
        bf16x8 vf0 = *(const bf16x8*)&Vt[l31][tb0 + hi * 8];
        bf16x8 vf1 = *(const bf16x8*)&Vt[l31][tb0 + 16 + hi * 8];

        // mask*log2e (LDS broadcast): t = tb0 + 8g + 4hi + {0..3}
        f32x4 mk0 = *(const f32x4*)&Ml[tb0 +  0 + 4 * hi];
        f32x4 mk1 = *(const f32x4*)&Ml[tb0 +  8 + 4 * hi];
        f32x4 mk2 = *(const f32x4*)&Ml[tb0 + 16 + 4 * hi];
        f32x4 mk3 = *(const f32x4*)&Ml[tb0 + 24 + 4 * hi];

        // QK^T
        __builtin_amdgcn_s_setprio(1);
        f32x16 cf = __builtin_amdgcn_mfma_f32_32x32x16_bf16(kf0, qf0, z16, 0, 0, 0);
        cf = __builtin_amdgcn_mfma_f32_32x32x16_bf16(kf1, qf1, cf, 0, 0, 0);
        __builtin_amdgcn_s_setprio(0);

        // softmax numerator + pack
        i32x2 a0 = pgrp<0>(cf, t0, mk0, lp);
        i32x2 a1 = pgrp<1>(cf, t1, mk1, lp);
        i32x2 a2 = pgrp<2>(cf, t2, mk2, lp);
        i32x2 a3 = pgrp<3>(cf, t3, mk3, lp);

        // tile maintenance: write chunk c+1 (regs loaded last iter), start c+2.
        // Safe vs the t0..t3 reads above: same-wave DS ops execute in order.
        if (c < 7) { STORE_TRI(); }
        if (c < 6) { LOAD_TRI(c + 2); }

        bf16x8 pa0, pa1;
        frags(a0, a1, a2, a3, pa0, pa1);

        __builtin_amdgcn_s_setprio(1);
        oacc = __builtin_amdgcn_mfma_f32_32x32x16_bf16(pa0, vf0, oacc, 0, 0, 0);
        oacc = __builtin_amdgcn_mfma_f32_32x32x16_bf16(pa1, vf1, oacc, 0, 0, 0);
        __builtin_amdgcn_s_setprio(0);
    }

    // ---- softmax denominator: hi-half reduce, then normalize + store ----
    lp += __shfl_xor(lp, 32);
    const float linv = 1.0f / lp;          // valid for s = qbase + l31

    float* ob = out + (size_t)inst * SEQ * DH;
    #pragma unroll
    for (int r = 0; r < 16; ++r) {
        const int srow = (r & 3) + 8 * (r >> 2) + 4 * hi;
        float invr = __shfl(linv, srow);   // 1/l for row srow lives in lane srow
        ob[(size_t)(qbase + srow) * DH + l31] = oacc[r] * invr;
    }
}

extern "C" void kernel_launch(void* const* d_in, const int* in_sizes, int n_in,
                              void* d_out, int out_size, void* d_ws, size_t ws_size,
                              hipStream_t stream) {
    const float* q    = (const float*)d_in[0];
    const float* k    = (const float*)d_in[1];
    const float* v    = (const float*)d_in[2];
    const float* mask = (const float*)d_in[3];
    const float* tri  = (const float*)d_in[4];
    float* out = (float*)d_out;

    attn_mfma_kernel<<<dim3(256 * 4), dim3(512), 0, stream>>>(q, k, v, mask, tri, out);
}